// Round 1
// baseline (456.025 us; speedup 1.0000x reference)
//
#include <hip/hip_runtime.h>

// MultiHeadedAttention: B=4 S=2048 D=1024 H=16 DK=64, fp32 in/out.
// cvt->bf16 (single fused launch); Q/K/V proj (128x128 MFMA GEMM, global_load_lds,
// XOR-swizzled LDS); bit-packed mask; St-layout flash attention with DOUBLE-BUFFERED
// K/V tiles + counted vmcnt(4) pipeline (T3-min) + setprio (T5); out proj GEMM.

#define B_ 4
#define S_ 2048
#define D_ 1024
#define H_ 16
#define DK_ 64
#define M_ (B_ * S_) // 8192

typedef __attribute__((ext_vector_type(4))) float f32x4;
typedef __attribute__((ext_vector_type(8))) short s16x8;
typedef __attribute__((ext_vector_type(8))) unsigned short u16x8;
typedef __attribute__((ext_vector_type(4))) unsigned short u16x4;

__device__ __forceinline__ unsigned short f2bf(float f) {
    union { float f; unsigned int u; } v; v.f = f;
    unsigned int u = v.u;
    return (unsigned short)((u + 0x7FFFu + ((u >> 16) & 1u)) >> 16); // RNE
}

__device__ __forceinline__ void gl2lds16(const unsigned short* g, unsigned short* l) {
    __builtin_amdgcn_global_load_lds((const __attribute__((address_space(1))) void*)g,
                                     (__attribute__((address_space(3))) void*)l, 16, 0, 0);
}

// ---------------- fp32 -> bf16 convert: all 7 tensors in ONE launch ----------------
// blocks 0..12287: query/key/value (4096 each); 12288..14335: w_q/w_k/w_v/w_o (512 each)
__global__ __launch_bounds__(256) void cvt_all(
    const float* __restrict__ q, const float* __restrict__ k, const float* __restrict__ v,
    const float* __restrict__ wq, const float* __restrict__ wk, const float* __restrict__ wv,
    const float* __restrict__ wo,
    unsigned short* __restrict__ Xq, unsigned short* __restrict__ Xk, unsigned short* __restrict__ Xv,
    unsigned short* __restrict__ Wq, unsigned short* __restrict__ Wk, unsigned short* __restrict__ Wv,
    unsigned short* __restrict__ Wo) {
    const int bid = blockIdx.x;
    const float* src;
    unsigned short* dst;
    int blk;
    if (bid < 12288) {
        const int t = bid >> 12;
        blk = bid & 4095;
        src = (t == 0) ? q : ((t == 1) ? k : v);
        dst = (t == 0) ? Xq : ((t == 1) ? Xk : Xv);
    } else {
        const int t = (bid - 12288) >> 9;
        blk = (bid - 12288) & 511;
        src = (t == 0) ? wq : ((t == 1) ? wk : ((t == 2) ? wv : wo));
        dst = (t == 0) ? Wq : ((t == 1) ? Wk : ((t == 2) ? Wv : Wo));
    }
    const int i = (blk * 256 + threadIdx.x) * 8;
    float4 a = *(const float4*)(src + i);
    float4 b = *(const float4*)(src + i + 4);
    u16x8 r;
    r[0] = f2bf(a.x); r[1] = f2bf(a.y); r[2] = f2bf(a.z); r[3] = f2bf(a.w);
    r[4] = f2bf(b.x); r[5] = f2bf(b.y); r[6] = f2bf(b.z); r[7] = f2bf(b.w);
    *(u16x8*)(dst + i) = r;
}

// ---------------- mask int32 -> bitmask ----------------
__global__ __launch_bounds__(256) void pack_mask(const int* __restrict__ m,
                                                 unsigned long long* __restrict__ pm) {
    int t = blockIdx.x * 256 + threadIdx.x;
    unsigned long long bits = __ballot(m[t] != 0);
    if ((threadIdx.x & 63) == 0) pm[t >> 6] = bits;
}

// ---------------- GEMM: Y[m][n] = (sum_k A[m][k]*Bt[n][k] + bias[n]) * scale --------
// 128x128 tile, BK=64, global_load_lds, XOR-swizzled LDS (conflict-free frag reads).
// MODE 1: bf16 -> (B,H,S,DK); MODE 2: bf16 -> (B,H,DK,S); MODE 3: fp32 M x 1024.
template <int MODE>
__global__ __launch_bounds__(256) void gemm_bt(const unsigned short* __restrict__ A,
                                               const unsigned short* __restrict__ Bt,
                                               const float* __restrict__ bias,
                                               float scale, void* __restrict__ Y) {
    __shared__ __align__(16) unsigned short As[128 * 64];
    __shared__ __align__(16) unsigned short Bs[128 * 64];
    const int tid = threadIdx.x;
    const int wave = tid >> 6, lane = tid & 63, quad = lane >> 4, l16 = lane & 15;
    const int m0 = blockIdx.x * 128, n0 = blockIdx.y * 128;
    const int rw = (wave & 1) * 64, cw = (wave >> 1) * 64;
    const int sw = l16 & 7;

    // staging: round r covers rows r*32..r*32+31; lane fetches swizzled chunk
    const int srow = tid >> 3, scol = ((tid & 7) ^ (srow & 7)) * 8;
    const unsigned short* ga = A + (size_t)(m0 + srow) * 1024 + scol;
    const unsigned short* gb = Bt + (size_t)(n0 + srow) * 1024 + scol;

    f32x4 acc[4][4];
#pragma unroll
    for (int mi = 0; mi < 4; mi++)
#pragma unroll
        for (int ni = 0; ni < 4; ni++) acc[mi][ni] = (f32x4){0.f, 0.f, 0.f, 0.f};

    for (int k0 = 0; k0 < 1024; k0 += 64) {
#pragma unroll
        for (int r = 0; r < 4; r++) {
            gl2lds16(ga + (size_t)(r * 32) * 1024 + k0, &As[(r * 256 + tid) * 8]);
            gl2lds16(gb + (size_t)(r * 32) * 1024 + k0, &Bs[(r * 256 + tid) * 8]);
        }
        __syncthreads();
#pragma unroll
        for (int kki = 0; kki < 2; kki++) {
            const int xo = ((kki * 4 + quad) ^ sw) * 8;
            s16x8 af[4], bf[4];
#pragma unroll
            for (int mi = 0; mi < 4; mi++)
                af[mi] = *(const s16x8*)&As[(rw + mi * 16 + l16) * 64 + xo];
#pragma unroll
            for (int ni = 0; ni < 4; ni++)
                bf[ni] = *(const s16x8*)&Bs[(cw + ni * 16 + l16) * 64 + xo];
#pragma unroll
            for (int mi = 0; mi < 4; mi++)
#pragma unroll
                for (int ni = 0; ni < 4; ni++)
                    acc[mi][ni] = __builtin_amdgcn_mfma_f32_16x16x32_bf16(af[mi], bf[ni], acc[mi][ni], 0, 0, 0);
        }
        __syncthreads();
    }

    float bv[4];
#pragma unroll
    for (int ni = 0; ni < 4; ni++) bv[ni] = bias[n0 + cw + ni * 16 + l16];
#pragma unroll
    for (int mi = 0; mi < 4; mi++) {
        const int rb = m0 + rw + mi * 16 + quad * 4;
        const int b = rb >> 11, s0 = rb & 2047;
#pragma unroll
        for (int ni = 0; ni < 4; ni++) {
            const int col = n0 + cw + ni * 16 + l16;
            if (MODE == 3) {
#pragma unroll
                for (int i = 0; i < 4; i++)
                    ((float*)Y)[(size_t)(rb + i) * 1024 + col] = (acc[mi][ni][i] + bv[ni]) * scale;
            } else {
                const int h = col >> 6, dk = col & 63;
                if (MODE == 1) {
#pragma unroll
                    for (int i = 0; i < 4; i++)
                        ((unsigned short*)Y)[((size_t)(b * H_ + h) * S_ + s0 + i) * DK_ + dk] =
                            f2bf((acc[mi][ni][i] + bv[ni]) * scale);
                } else {
                    u16x4 pk;
#pragma unroll
                    for (int i = 0; i < 4; i++) pk[i] = f2bf((acc[mi][ni][i] + bv[ni]) * scale);
                    *(u16x4*)&((unsigned short*)Y)[((size_t)(b * H_ + h) * DK_ + dk) * S_ + s0] = pk;
                }
            }
        }
    }
}

// ---------------- Flash attention (St layout, swizzled LDS, 2-phase dbuf) ----------
// Grid (S/128, B*H), block 256 = 4 waves; wave owns 32 q rows (2 blocks of 16).
// St = K*Q^T: C col = q = lane&15, row = k = ct*16+quad*4+i.
// p = exp2(s) AND sbfe-mask; P packed bf16 pairs via v_perm; l via mfma(P, ones).
// K/V tiles double-buffered: prefetch kt+1 before computing kt; counted vmcnt(4)
// + raw s_barrier (NOT __syncthreads -> no vmcnt(0) drain). Mask loads hoisted
// ABOVE the prefetch so their consumption waits vmcnt(4), not vmcnt(0).
__global__ __launch_bounds__(256) void attn_kernel(const unsigned short* __restrict__ Q,
                                                   const unsigned short* __restrict__ K,
                                                   const unsigned short* __restrict__ Vt,
                                                   const unsigned long long* __restrict__ pm,
                                                   unsigned short* __restrict__ ctx) {
    __shared__ __align__(16) unsigned short Ks[2][64 * 64];
    __shared__ __align__(16) unsigned short Vs[2][64 * 64];
    __shared__ __align__(16) unsigned short Ps[8 * 16 * 64]; // swizzled strips

    const int tid = threadIdx.x;
    const int wave = tid >> 6, lane = tid & 63, quad = lane >> 4, l16 = lane & 15;
    const int bh = blockIdx.y, b = bh >> 4, h = bh & 15;
    const int q0 = blockIdx.x * 128;
    const int qbase = q0 + wave * 32;
    const int sw = l16 & 7, q4 = quad * 4, qh = quad >> 1;

    const unsigned short* Kbase = K + (size_t)bh * S_ * DK_;
    const unsigned short* Vbase = Vt + (size_t)bh * DK_ * S_;

    // Q fragments (B-operand): B[n=q=l16][k=d]
    s16x8 qf[2][2];
#pragma unroll
    for (int qb = 0; qb < 2; qb++) {
        const unsigned short* qr = Q + ((size_t)bh * S_ + qbase + qb * 16 + l16) * DK_ + quad * 8;
        qf[qb][0] = *(const s16x8*)qr;
        qf[qb][1] = *(const s16x8*)(qr + 32);
    }
    // mask row pointers (per qb), advanced by kt
    const unsigned long long* pmq[2];
#pragma unroll
    for (int qb = 0; qb < 2; qb++)
        pmq[qb] = pm + ((size_t)b * S_ + qbase + qb * 16 + l16) * 32;

    s16x8 ones;
#pragma unroll
    for (int j = 0; j < 8; j++) ones[j] = (short)0x3F80; // bf16 1.0

    f32x4 oacc[2][4], lacc[2];
#pragma unroll
    for (int qb = 0; qb < 2; qb++) {
        lacc[qb] = (f32x4){0.f, 0.f, 0.f, 0.f};
#pragma unroll
        for (int ct = 0; ct < 4; ct++) oacc[qb][ct] = (f32x4){0.f, 0.f, 0.f, 0.f};
    }

    const int sr = tid >> 3, sc = ((tid & 7) ^ (sr & 7)) * 8;
    const unsigned short* Kg0 = Kbase + (size_t)sr * DK_ + sc;
    const unsigned short* Kg1 = Kbase + (size_t)(32 + sr) * DK_ + sc;
    const unsigned short* Vg0 = Vbase + (size_t)sr * S_ + sc;
    const unsigned short* Vg1 = Vbase + (size_t)(32 + sr) * S_ + sc;

    // prologue: stage tile 0 into buffer 0 (4 outstanding vmem ops)
    gl2lds16(Kg0, &Ks[0][tid * 8]);
    gl2lds16(Kg1, &Ks[0][2048 + tid * 8]);
    gl2lds16(Vg0, &Vs[0][tid * 8]);
    gl2lds16(Vg1, &Vs[0][2048 + tid * 8]);

    for (int kt = 0; kt < S_ / 64; kt++) {
        const int cur = kt & 1;

        // mask loads for THIS tile, issued before the prefetch: their consumption
        // then only needs vmcnt(4) (prefetch stays in flight).
        uint2 mv[2];
        mv[0] = *(const uint2*)&pmq[0][kt];
        mv[1] = *(const uint2*)&pmq[1][kt];
        __builtin_amdgcn_sched_barrier(0); // pin: masks issue BEFORE prefetch gl2lds

        if (kt + 1 < S_ / 64) {
            const int k1 = (kt + 1) * 64;
            const int nb = cur ^ 1;
            gl2lds16(Kg0 + (size_t)k1 * DK_, &Ks[nb][tid * 8]);
            gl2lds16(Kg1 + (size_t)k1 * DK_, &Ks[nb][2048 + tid * 8]);
            gl2lds16(Vg0 + k1, &Vs[nb][tid * 8]);
            gl2lds16(Vg1 + k1, &Vs[nb][2048 + tid * 8]);
            asm volatile("s_waitcnt vmcnt(4)" ::: "memory"); // cur tile + masks done
        } else {
            asm volatile("s_waitcnt vmcnt(0)" ::: "memory");
        }
        __builtin_amdgcn_s_barrier();

        // St = K * Q^T
        f32x4 sacc[2][4];
#pragma unroll
        for (int qb = 0; qb < 2; qb++)
#pragma unroll
            for (int ct = 0; ct < 4; ct++) sacc[qb][ct] = (f32x4){0.f, 0.f, 0.f, 0.f};
#pragma unroll
        for (int kki = 0; kki < 2; kki++) {
            const int xo = ((kki * 4 + quad) ^ sw) * 8;
            s16x8 kf[4];
#pragma unroll
            for (int ct = 0; ct < 4; ct++)
                kf[ct] = *(const s16x8*)&Ks[cur][(ct * 16 + l16) * 64 + xo];
            __builtin_amdgcn_s_setprio(1);
#pragma unroll
            for (int qb = 0; qb < 2; qb++)
#pragma unroll
                for (int ct = 0; ct < 4; ct++)
                    sacc[qb][ct] = __builtin_amdgcn_mfma_f32_16x16x32_bf16(kf[ct], qf[qb][kki], sacc[qb][ct], 0, 0, 0);
            __builtin_amdgcn_s_setprio(0);
        }

        // mask (sbfe) + exp2 + perm-pack + swizzled strip write
#pragma unroll
        for (int qb = 0; qb < 2; qb++) {
            unsigned short* pwq = &Ps[(wave * 2 + qb) * 1024];
            const unsigned mqx = mv[qb].x >> q4;
            const unsigned mqy = mv[qb].y >> q4;
#pragma unroll
            for (int ct = 0; ct < 4; ct++) {
                const unsigned mq = (ct & 2) ? mqy : mqx;
                unsigned pu[4];
#pragma unroll
                for (int i = 0; i < 4; i++) {
                    const int pos = (ct & 1) * 16 + i;
                    const int mb = __builtin_amdgcn_sbfe(mq, pos, 1); // 0 or -1
                    const float p = exp2f(sacc[qb][ct][i]);
                    pu[i] = __float_as_uint(p) & (unsigned)mb;
                }
                const int ch = ((2 * ct + qh) ^ sw) * 8;
#pragma unroll
                for (int t = 0; t < 2; t++) {
                    const unsigned pk = __builtin_amdgcn_perm(pu[2 * t + 1], pu[2 * t], 0x07060302u);
                    *(unsigned*)&pwq[l16 * 64 + ch + ((q4 + 2 * t) & 7)] = pk;
                }
            }
        }

        // O += P*V ; l += P*ones  (strips wave-private; in-wave lgkm ordering)
#pragma unroll
        for (int kki = 0; kki < 2; kki++) {
            const int xo = ((kki * 4 + quad) ^ sw) * 8;
            s16x8 vf[4];
#pragma unroll
            for (int ct = 0; ct < 4; ct++)
                vf[ct] = *(const s16x8*)&Vs[cur][(ct * 16 + l16) * 64 + xo];
#pragma unroll
            for (int qb = 0; qb < 2; qb++) {
                s16x8 pf = *(const s16x8*)&Ps[(wave * 2 + qb) * 1024 + l16 * 64 + xo];
                __builtin_amdgcn_s_setprio(1);
#pragma unroll
                for (int ct = 0; ct < 4; ct++)
                    oacc[qb][ct] = __builtin_amdgcn_mfma_f32_16x16x32_bf16(pf, vf[ct], oacc[qb][ct], 0, 0, 0);
                lacc[qb] = __builtin_amdgcn_mfma_f32_16x16x32_bf16(pf, ones, lacc[qb], 0, 0, 0);
                __builtin_amdgcn_s_setprio(0);
            }
        }

        asm volatile("s_waitcnt lgkmcnt(0)" ::: "memory"); // my LDS reads retired
        __builtin_amdgcn_s_barrier();                      // safe to overwrite cur next iter
    }

    // epilogue: O rows (q=quad*4+i) align with lacc rows; normalize + write
#pragma unroll
    for (int qb = 0; qb < 2; qb++) {
        f32x4 rl;
#pragma unroll
        for (int i = 0; i < 4; i++) rl[i] = 1.0f / lacc[qb][i];
#pragma unroll
        for (int ct = 0; ct < 4; ct++) {
            const int col = h * DK_ + ct * 16 + l16;
#pragma unroll
            for (int i = 0; i < 4; i++) {
                const int sg = qbase + qb * 16 + quad * 4 + i;
                ctx[((size_t)(b * S_ + sg)) * D_ + col] = f2bf(oacc[qb][ct][i] * rl[i]);
            }
        }
    }
}

// ---------------- launch ----------------
extern "C" void kernel_launch(void* const* d_in, const int* in_sizes, int n_in,
                              void* d_out, int out_size, void* d_ws, size_t ws_size,
                              hipStream_t stream) {
    const float* query = (const float*)d_in[0];
    const float* key   = (const float*)d_in[1];
    const float* value = (const float*)d_in[2];
    const int*   mask  = (const int*)d_in[3];
    const float* w_q = (const float*)d_in[4];
    const float* b_q = (const float*)d_in[5];
    const float* w_k = (const float*)d_in[6];
    const float* b_k = (const float*)d_in[7];
    const float* w_v = (const float*)d_in[8];
    const float* b_v = (const float*)d_in[9];
    const float* w_o = (const float*)d_in[10];
    const float* b_o = (const float*)d_in[11];

    char* ws = (char*)d_ws;
    const size_t XSZ = (size_t)M_ * D_ * 2;  // 16 MB
    const size_t WSZ = (size_t)D_ * D_ * 2;  // 2 MB
    unsigned short* Xq  = (unsigned short*)(ws);
    unsigned short* Xk  = (unsigned short*)(ws + XSZ);
    unsigned short* Xv  = (unsigned short*)(ws + 2 * XSZ);
    unsigned short* Wq  = (unsigned short*)(ws + 3 * XSZ);
    unsigned short* Wk  = (unsigned short*)(ws + 3 * XSZ + WSZ);
    unsigned short* Wv  = (unsigned short*)(ws + 3 * XSZ + 2 * WSZ);
    unsigned short* Wo  = (unsigned short*)(ws + 3 * XSZ + 3 * WSZ);
    unsigned short* Qb  = (unsigned short*)(ws + 3 * XSZ + 4 * WSZ);
    unsigned short* Kb  = (unsigned short*)(ws + 4 * XSZ + 4 * WSZ);
    unsigned short* Vtb = (unsigned short*)(ws + 5 * XSZ + 4 * WSZ);
    unsigned short* ctx = (unsigned short*)(ws + 6 * XSZ + 4 * WSZ);
    unsigned long long* pm = (unsigned long long*)(ws); // overlaps Xq (dead after Q GEMM)

    // all 7 fp32->bf16 converts in one launch (3*4096 + 4*512 = 14336 blocks)
    hipLaunchKernelGGL(cvt_all, dim3(14336), dim3(256), 0, stream,
                       query, key, value, w_q, w_k, w_v, w_o,
                       Xq, Xk, Xv, Wq, Wk, Wv, Wo);

    const float QSCALE = 0.125f * 1.44269504f; // fold /sqrt(DK) and log2(e) into Q
    dim3 ggrid(M_ / 128, D_ / 128); // 64 x 8
    hipLaunchKernelGGL(HIP_KERNEL_NAME(gemm_bt<1>), ggrid, dim3(256), 0, stream, Xq, Wq, b_q, QSCALE, (void*)Qb);
    hipLaunchKernelGGL(HIP_KERNEL_NAME(gemm_bt<1>), ggrid, dim3(256), 0, stream, Xk, Wk, b_k, 1.0f, (void*)Kb);
    hipLaunchKernelGGL(HIP_KERNEL_NAME(gemm_bt<2>), ggrid, dim3(256), 0, stream, Xv, Wv, b_v, 1.0f, (void*)Vtb);

    hipLaunchKernelGGL(pack_mask, dim3((B_ * S_ * S_) / 256), dim3(256), 0, stream, mask, pm);

    hipLaunchKernelGGL(attn_kernel, dim3(S_ / 128, B_ * H_), dim3(256), 0, stream,
                       Qb, Kb, Vtb, pm, ctx);

    hipLaunchKernelGGL(HIP_KERNEL_NAME(gemm_bt<3>), ggrid, dim3(256), 0, stream, ctx, Wo, b_o, 1.0f, d_out);
}

// Round 2
// 430.573 us; speedup vs baseline: 1.0591x; 1.0591x over previous
//
#include <hip/hip_runtime.h>

// MultiHeadedAttention: B=4 S=2048 D=1024 H=16 DK=64, fp32 in/out.
// cvt->bf16 (single fused launch); Q/K/V proj (128x128 MFMA GEMM, global_load_lds,
// XOR-swizzled LDS); bit-packed mask; St-layout flash attention with DOUBLE-BUFFERED
// K/V tiles + counted vmcnt(4) pipeline + setprio; P stays IN REGISTERS via
// v_permlane{32,16}_swap_b32 (no Ps LDS round-trip; LDS 48KB->32KB => 5 blocks/CU);
// out proj GEMM.

#define B_ 4
#define S_ 2048
#define D_ 1024
#define H_ 16
#define DK_ 64
#define M_ (B_ * S_) // 8192

typedef __attribute__((ext_vector_type(4))) float f32x4;
typedef __attribute__((ext_vector_type(8))) short s16x8;
typedef __attribute__((ext_vector_type(8))) unsigned short u16x8;
typedef __attribute__((ext_vector_type(4))) unsigned short u16x4;

__device__ __forceinline__ unsigned short f2bf(float f) {
    union { float f; unsigned int u; } v; v.f = f;
    unsigned int u = v.u;
    return (unsigned short)((u + 0x7FFFu + ((u >> 16) & 1u)) >> 16); // RNE
}

__device__ __forceinline__ void gl2lds16(const unsigned short* g, unsigned short* l) {
    __builtin_amdgcn_global_load_lds((const __attribute__((address_space(1))) void*)g,
                                     (__attribute__((address_space(3))) void*)l, 16, 0, 0);
}

// ---------------- fp32 -> bf16 convert: all 7 tensors in ONE launch ----------------
// blocks 0..12287: query/key/value (4096 each); 12288..14335: w_q/w_k/w_v/w_o (512 each)
__global__ __launch_bounds__(256) void cvt_all(
    const float* __restrict__ q, const float* __restrict__ k, const float* __restrict__ v,
    const float* __restrict__ wq, const float* __restrict__ wk, const float* __restrict__ wv,
    const float* __restrict__ wo,
    unsigned short* __restrict__ Xq, unsigned short* __restrict__ Xk, unsigned short* __restrict__ Xv,
    unsigned short* __restrict__ Wq, unsigned short* __restrict__ Wk, unsigned short* __restrict__ Wv,
    unsigned short* __restrict__ Wo) {
    const int bid = blockIdx.x;
    const float* src;
    unsigned short* dst;
    int blk;
    if (bid < 12288) {
        const int t = bid >> 12;
        blk = bid & 4095;
        src = (t == 0) ? q : ((t == 1) ? k : v);
        dst = (t == 0) ? Xq : ((t == 1) ? Xk : Xv);
    } else {
        const int t = (bid - 12288) >> 9;
        blk = (bid - 12288) & 511;
        src = (t == 0) ? wq : ((t == 1) ? wk : ((t == 2) ? wv : wo));
        dst = (t == 0) ? Wq : ((t == 1) ? Wk : ((t == 2) ? Wv : Wo));
    }
    const int i = (blk * 256 + threadIdx.x) * 8;
    float4 a = *(const float4*)(src + i);
    float4 b = *(const float4*)(src + i + 4);
    u16x8 r;
    r[0] = f2bf(a.x); r[1] = f2bf(a.y); r[2] = f2bf(a.z); r[3] = f2bf(a.w);
    r[4] = f2bf(b.x); r[5] = f2bf(b.y); r[6] = f2bf(b.z); r[7] = f2bf(b.w);
    *(u16x8*)(dst + i) = r;
}

// ---------------- mask int32 -> bitmask ----------------
__global__ __launch_bounds__(256) void pack_mask(const int* __restrict__ m,
                                                 unsigned long long* __restrict__ pm) {
    int t = blockIdx.x * 256 + threadIdx.x;
    unsigned long long bits = __ballot(m[t] != 0);
    if ((threadIdx.x & 63) == 0) pm[t >> 6] = bits;
}

// ---------------- GEMM: Y[m][n] = (sum_k A[m][k]*Bt[n][k] + bias[n]) * scale --------
// 128x128 tile, BK=64, global_load_lds, XOR-swizzled LDS (conflict-free frag reads).
// MODE 1: bf16 -> (B,H,S,DK); MODE 2: bf16 -> (B,H,DK,S); MODE 3: fp32 M x 1024.
template <int MODE>
__global__ __launch_bounds__(256) void gemm_bt(const unsigned short* __restrict__ A,
                                               const unsigned short* __restrict__ Bt,
                                               const float* __restrict__ bias,
                                               float scale, void* __restrict__ Y) {
    __shared__ __align__(16) unsigned short As[128 * 64];
    __shared__ __align__(16) unsigned short Bs[128 * 64];
    const int tid = threadIdx.x;
    const int wave = tid >> 6, lane = tid & 63, quad = lane >> 4, l16 = lane & 15;
    const int m0 = blockIdx.x * 128, n0 = blockIdx.y * 128;
    const int rw = (wave & 1) * 64, cw = (wave >> 1) * 64;
    const int sw = l16 & 7;

    // staging: round r covers rows r*32..r*32+31; lane fetches swizzled chunk
    const int srow = tid >> 3, scol = ((tid & 7) ^ (srow & 7)) * 8;
    const unsigned short* ga = A + (size_t)(m0 + srow) * 1024 + scol;
    const unsigned short* gb = Bt + (size_t)(n0 + srow) * 1024 + scol;

    f32x4 acc[4][4];
#pragma unroll
    for (int mi = 0; mi < 4; mi++)
#pragma unroll
        for (int ni = 0; ni < 4; ni++) acc[mi][ni] = (f32x4){0.f, 0.f, 0.f, 0.f};

    for (int k0 = 0; k0 < 1024; k0 += 64) {
#pragma unroll
        for (int r = 0; r < 4; r++) {
            gl2lds16(ga + (size_t)(r * 32) * 1024 + k0, &As[(r * 256 + tid) * 8]);
            gl2lds16(gb + (size_t)(r * 32) * 1024 + k0, &Bs[(r * 256 + tid) * 8]);
        }
        __syncthreads();
#pragma unroll
        for (int kki = 0; kki < 2; kki++) {
            const int xo = ((kki * 4 + quad) ^ sw) * 8;
            s16x8 af[4], bf[4];
#pragma unroll
            for (int mi = 0; mi < 4; mi++)
                af[mi] = *(const s16x8*)&As[(rw + mi * 16 + l16) * 64 + xo];
#pragma unroll
            for (int ni = 0; ni < 4; ni++)
                bf[ni] = *(const s16x8*)&Bs[(cw + ni * 16 + l16) * 64 + xo];
#pragma unroll
            for (int mi = 0; mi < 4; mi++)
#pragma unroll
                for (int ni = 0; ni < 4; ni++)
                    acc[mi][ni] = __builtin_amdgcn_mfma_f32_16x16x32_bf16(af[mi], bf[ni], acc[mi][ni], 0, 0, 0);
        }
        __syncthreads();
    }

    float bv[4];
#pragma unroll
    for (int ni = 0; ni < 4; ni++) bv[ni] = bias[n0 + cw + ni * 16 + l16];
#pragma unroll
    for (int mi = 0; mi < 4; mi++) {
        const int rb = m0 + rw + mi * 16 + quad * 4;
        const int b = rb >> 11, s0 = rb & 2047;
#pragma unroll
        for (int ni = 0; ni < 4; ni++) {
            const int col = n0 + cw + ni * 16 + l16;
            if (MODE == 3) {
#pragma unroll
                for (int i = 0; i < 4; i++)
                    ((float*)Y)[(size_t)(rb + i) * 1024 + col] = (acc[mi][ni][i] + bv[ni]) * scale;
            } else {
                const int h = col >> 6, dk = col & 63;
                if (MODE == 1) {
#pragma unroll
                    for (int i = 0; i < 4; i++)
                        ((unsigned short*)Y)[((size_t)(b * H_ + h) * S_ + s0 + i) * DK_ + dk] =
                            f2bf((acc[mi][ni][i] + bv[ni]) * scale);
                } else {
                    u16x4 pk;
#pragma unroll
                    for (int i = 0; i < 4; i++) pk[i] = f2bf((acc[mi][ni][i] + bv[ni]) * scale);
                    *(u16x4*)&((unsigned short*)Y)[((size_t)(b * H_ + h) * DK_ + dk) * S_ + s0] = pk;
                }
            }
        }
    }
}

// ---------------- Flash attention (St layout, register-P, 2-phase dbuf) ----------
// Grid (S/128, B*H), block 256 = 4 waves; wave owns 32 q rows (2 blocks of 16).
// St = K*Q^T: C col = q = lane&15, row = k = ct*16+quad*4+i.
// p = exp2(s) AND sbfe-mask; P packed bf16 pairs via v_perm; P->A-fragment
// rearrangement IN REGISTERS via v_permlane32_swap + v_permlane16_swap:
//   A = pk[2kki][t] (quads a0..a3), B = pk[2kki+1][t] (b0..b3)
//   permlane32_swap: A=(a0,a1,b0,b1) B=(a2,a3,b2,b3)
//   permlane16_swap: A=(a0,a2,b0,b2)=word(t) B=(a1,a3,b1,b3)=word(2+t)
// l via mfma(P, ones). K/V double-buffered, counted vmcnt(4), raw s_barrier.
__global__ __launch_bounds__(256) void attn_kernel(const unsigned short* __restrict__ Q,
                                                   const unsigned short* __restrict__ K,
                                                   const unsigned short* __restrict__ Vt,
                                                   const unsigned long long* __restrict__ pm,
                                                   unsigned short* __restrict__ ctx) {
    __shared__ __align__(16) unsigned short Ks[2][64 * 64];
    __shared__ __align__(16) unsigned short Vs[2][64 * 64];

    const int tid = threadIdx.x;
    const int wave = tid >> 6, lane = tid & 63, quad = lane >> 4, l16 = lane & 15;
    const int bh = blockIdx.y, b = bh >> 4, h = bh & 15;
    const int q0 = blockIdx.x * 128;
    const int qbase = q0 + wave * 32;
    const int sw = l16 & 7, q4 = quad * 4;

    const unsigned short* Kbase = K + (size_t)bh * S_ * DK_;
    const unsigned short* Vbase = Vt + (size_t)bh * DK_ * S_;

    // Q fragments (B-operand): B[n=q=l16][k=d]
    s16x8 qf[2][2];
#pragma unroll
    for (int qb = 0; qb < 2; qb++) {
        const unsigned short* qr = Q + ((size_t)bh * S_ + qbase + qb * 16 + l16) * DK_ + quad * 8;
        qf[qb][0] = *(const s16x8*)qr;
        qf[qb][1] = *(const s16x8*)(qr + 32);
    }
    // mask row pointers (per qb), advanced by kt
    const unsigned long long* pmq[2];
#pragma unroll
    for (int qb = 0; qb < 2; qb++)
        pmq[qb] = pm + ((size_t)b * S_ + qbase + qb * 16 + l16) * 32;

    s16x8 ones;
#pragma unroll
    for (int j = 0; j < 8; j++) ones[j] = (short)0x3F80; // bf16 1.0

    f32x4 oacc[2][4], lacc[2];
#pragma unroll
    for (int qb = 0; qb < 2; qb++) {
        lacc[qb] = (f32x4){0.f, 0.f, 0.f, 0.f};
#pragma unroll
        for (int ct = 0; ct < 4; ct++) oacc[qb][ct] = (f32x4){0.f, 0.f, 0.f, 0.f};
    }

    const int sr = tid >> 3, sc = ((tid & 7) ^ (sr & 7)) * 8;
    const unsigned short* Kg0 = Kbase + (size_t)sr * DK_ + sc;
    const unsigned short* Kg1 = Kbase + (size_t)(32 + sr) * DK_ + sc;
    const unsigned short* Vg0 = Vbase + (size_t)sr * S_ + sc;
    const unsigned short* Vg1 = Vbase + (size_t)(32 + sr) * S_ + sc;

    // prologue: stage tile 0 into buffer 0 (4 outstanding vmem ops)
    gl2lds16(Kg0, &Ks[0][tid * 8]);
    gl2lds16(Kg1, &Ks[0][2048 + tid * 8]);
    gl2lds16(Vg0, &Vs[0][tid * 8]);
    gl2lds16(Vg1, &Vs[0][2048 + tid * 8]);

    for (int kt = 0; kt < S_ / 64; kt++) {
        const int cur = kt & 1;

        // mask loads for THIS tile, issued before the prefetch: their consumption
        // then only needs vmcnt(4) (prefetch stays in flight).
        uint2 mv[2];
        mv[0] = *(const uint2*)&pmq[0][kt];
        mv[1] = *(const uint2*)&pmq[1][kt];
        __builtin_amdgcn_sched_barrier(0); // pin: masks issue BEFORE prefetch gl2lds

        if (kt + 1 < S_ / 64) {
            const int k1 = (kt + 1) * 64;
            const int nb = cur ^ 1;
            gl2lds16(Kg0 + (size_t)k1 * DK_, &Ks[nb][tid * 8]);
            gl2lds16(Kg1 + (size_t)k1 * DK_, &Ks[nb][2048 + tid * 8]);
            gl2lds16(Vg0 + k1, &Vs[nb][tid * 8]);
            gl2lds16(Vg1 + k1, &Vs[nb][2048 + tid * 8]);
            asm volatile("s_waitcnt vmcnt(4)" ::: "memory"); // cur tile + masks done
        } else {
            asm volatile("s_waitcnt vmcnt(0)" ::: "memory");
        }
        __builtin_amdgcn_s_barrier();

        // St = K * Q^T
        f32x4 sacc[2][4];
#pragma unroll
        for (int qb = 0; qb < 2; qb++)
#pragma unroll
            for (int ct = 0; ct < 4; ct++) sacc[qb][ct] = (f32x4){0.f, 0.f, 0.f, 0.f};
#pragma unroll
        for (int kki = 0; kki < 2; kki++) {
            const int xo = ((kki * 4 + quad) ^ sw) * 8;
            s16x8 kf[4];
#pragma unroll
            for (int ct = 0; ct < 4; ct++)
                kf[ct] = *(const s16x8*)&Ks[cur][(ct * 16 + l16) * 64 + xo];
            __builtin_amdgcn_s_setprio(1);
#pragma unroll
            for (int qb = 0; qb < 2; qb++)
#pragma unroll
                for (int ct = 0; ct < 4; ct++)
                    sacc[qb][ct] = __builtin_amdgcn_mfma_f32_16x16x32_bf16(kf[ct], qf[qb][kki], sacc[qb][ct], 0, 0, 0);
            __builtin_amdgcn_s_setprio(0);
        }

        // mask (sbfe) + exp2 + perm-pack -> P pairs in registers
        // pk[qb][ct][t] lane(quad,l16=q) = bf16x2 P[k=ct*16+quad*4+2t(+1)][q]
        unsigned pk[2][4][2];
#pragma unroll
        for (int qb = 0; qb < 2; qb++) {
            const unsigned mqx = mv[qb].x >> q4;
            const unsigned mqy = mv[qb].y >> q4;
#pragma unroll
            for (int ct = 0; ct < 4; ct++) {
                const unsigned mq = (ct & 2) ? mqy : mqx;
#pragma unroll
                for (int t = 0; t < 2; t++) {
                    const int pos = (ct & 1) * 16 + 2 * t;
                    const int mb0 = __builtin_amdgcn_sbfe(mq, pos, 1);     // 0 or -1
                    const int mb1 = __builtin_amdgcn_sbfe(mq, pos + 1, 1);
                    const unsigned p0 =
                        __float_as_uint(__builtin_amdgcn_exp2f(sacc[qb][ct][2 * t])) & (unsigned)mb0;
                    const unsigned p1 =
                        __float_as_uint(__builtin_amdgcn_exp2f(sacc[qb][ct][2 * t + 1])) & (unsigned)mb1;
                    pk[qb][ct][t] = __builtin_amdgcn_perm(p1, p0, 0x07060302u);
                }
            }
        }

        // O += P*V ; l += P*ones  (P rearranged quad-wise via permlane swaps)
#pragma unroll
        for (int kki = 0; kki < 2; kki++) {
            const int xo = ((kki * 4 + quad) ^ sw) * 8;
            s16x8 vf[4];
#pragma unroll
            for (int ct = 0; ct < 4; ct++)
                vf[ct] = *(const s16x8*)&Vs[cur][(ct * 16 + l16) * 64 + xo];
#pragma unroll
            for (int qb = 0; qb < 2; qb++) {
                unsigned w0 = pk[qb][2 * kki][0], w2 = pk[qb][2 * kki + 1][0];
                unsigned w1 = pk[qb][2 * kki][1], w3 = pk[qb][2 * kki + 1][1];
                asm("v_permlane32_swap_b32 %0, %1" : "+v"(w0), "+v"(w2));
                asm("v_permlane16_swap_b32 %0, %1" : "+v"(w0), "+v"(w2));
                asm("v_permlane32_swap_b32 %0, %1" : "+v"(w1), "+v"(w3));
                asm("v_permlane16_swap_b32 %0, %1" : "+v"(w1), "+v"(w3));
                union { unsigned u[4]; s16x8 v; } pfu;
                pfu.u[0] = w0; pfu.u[1] = w1; pfu.u[2] = w2; pfu.u[3] = w3;
                const s16x8 pf = pfu.v;
                __builtin_amdgcn_s_setprio(1);
#pragma unroll
                for (int ct = 0; ct < 4; ct++)
                    oacc[qb][ct] = __builtin_amdgcn_mfma_f32_16x16x32_bf16(pf, vf[ct], oacc[qb][ct], 0, 0, 0);
                lacc[qb] = __builtin_amdgcn_mfma_f32_16x16x32_bf16(pf, ones, lacc[qb], 0, 0, 0);
                __builtin_amdgcn_s_setprio(0);
            }
        }

        asm volatile("s_waitcnt lgkmcnt(0)" ::: "memory"); // my LDS reads retired
        __builtin_amdgcn_s_barrier();                      // safe to overwrite cur next iter
    }

    // epilogue: O rows (q=quad*4+i) align with lacc rows; normalize + write
#pragma unroll
    for (int qb = 0; qb < 2; qb++) {
        f32x4 rl;
#pragma unroll
        for (int i = 0; i < 4; i++) rl[i] = 1.0f / lacc[qb][i];
#pragma unroll
        for (int ct = 0; ct < 4; ct++) {
            const int col = h * DK_ + ct * 16 + l16;
#pragma unroll
            for (int i = 0; i < 4; i++) {
                const int sg = qbase + qb * 16 + quad * 4 + i;
                ctx[((size_t)(b * S_ + sg)) * D_ + col] = f2bf(oacc[qb][ct][i] * rl[i]);
            }
        }
    }
}

// ---------------- launch ----------------
extern "C" void kernel_launch(void* const* d_in, const int* in_sizes, int n_in,
                              void* d_out, int out_size, void* d_ws, size_t ws_size,
                              hipStream_t stream) {
    const float* query = (const float*)d_in[0];
    const float* key   = (const float*)d_in[1];
    const float* value = (const float*)d_in[2];
    const int*   mask  = (const int*)d_in[3];
    const float* w_q = (const float*)d_in[4];
    const float* b_q = (const float*)d_in[5];
    const float* w_k = (const float*)d_in[6];
    const float* b_k = (const float*)d_in[7];
    const float* w_v = (const float*)d_in[8];
    const float* b_v = (const float*)d_in[9];
    const float* w_o = (const float*)d_in[10];
    const float* b_o = (const float*)d_in[11];

    char* ws = (char*)d_ws;
    const size_t XSZ = (size_t)M_ * D_ * 2;  // 16 MB
    const size_t WSZ = (size_t)D_ * D_ * 2;  // 2 MB
    unsigned short* Xq  = (unsigned short*)(ws);
    unsigned short* Xk  = (unsigned short*)(ws + XSZ);
    unsigned short* Xv  = (unsigned short*)(ws + 2 * XSZ);
    unsigned short* Wq  = (unsigned short*)(ws + 3 * XSZ);
    unsigned short* Wk  = (unsigned short*)(ws + 3 * XSZ + WSZ);
    unsigned short* Wv  = (unsigned short*)(ws + 3 * XSZ + 2 * WSZ);
    unsigned short* Wo  = (unsigned short*)(ws + 3 * XSZ + 3 * WSZ);
    unsigned short* Qb  = (unsigned short*)(ws + 3 * XSZ + 4 * WSZ);
    unsigned short* Kb  = (unsigned short*)(ws + 4 * XSZ + 4 * WSZ);
    unsigned short* Vtb = (unsigned short*)(ws + 5 * XSZ + 4 * WSZ);
    unsigned short* ctx = (unsigned short*)(ws + 6 * XSZ + 4 * WSZ);
    unsigned long long* pm = (unsigned long long*)(ws); // overlaps Xq (dead after Q GEMM)

    // all 7 fp32->bf16 converts in one launch (3*4096 + 4*512 = 14336 blocks)
    hipLaunchKernelGGL(cvt_all, dim3(14336), dim3(256), 0, stream,
                       query, key, value, w_q, w_k, w_v, w_o,
                       Xq, Xk, Xv, Wq, Wk, Wv, Wo);

    const float QSCALE = 0.125f * 1.44269504f; // fold /sqrt(DK) and log2(e) into Q
    dim3 ggrid(M_ / 128, D_ / 128); // 64 x 8
    hipLaunchKernelGGL(HIP_KERNEL_NAME(gemm_bt<1>), ggrid, dim3(256), 0, stream, Xq, Wq, b_q, QSCALE, (void*)Qb);
    hipLaunchKernelGGL(HIP_KERNEL_NAME(gemm_bt<1>), ggrid, dim3(256), 0, stream, Xk, Wk, b_k, 1.0f, (void*)Kb);
    hipLaunchKernelGGL(HIP_KERNEL_NAME(gemm_bt<2>), ggrid, dim3(256), 0, stream, Xv, Wv, b_v, 1.0f, (void*)Vtb);

    hipLaunchKernelGGL(pack_mask, dim3((B_ * S_ * S_) / 256), dim3(256), 0, stream, mask, pm);

    hipLaunchKernelGGL(attn_kernel, dim3(S_ / 128, B_ * H_), dim3(256), 0, stream,
                       Qb, Kb, Vtb, pm, ctx);

    hipLaunchKernelGGL(HIP_KERNEL_NAME(gemm_bt<3>), ggrid, dim3(256), 0, stream, ctx, Wo, b_o, 1.0f, d_out);
}

// Round 3
// 415.840 us; speedup vs baseline: 1.0966x; 1.0354x over previous
//
#include <hip/hip_runtime.h>

// MultiHeadedAttention: B=4 S=2048 D=1024 H=16 DK=64, fp32 in/out.
// cvt->bf16 (single fused launch); fused QKV proj (one grid.z=3 dispatch, 128x128
// MFMA GEMM, global_load_lds, XOR-swizzled LDS); bit-packed mask; St-layout flash
// attention with double-buffered K/V tiles + DOUBLE-BUFFERED MASK REGS + counted
// vmcnt(6) pipeline + setprio; register-P via v_permlane{32,16}_swap; out proj GEMM.

#define B_ 4
#define S_ 2048
#define D_ 1024
#define H_ 16
#define DK_ 64
#define M_ (B_ * S_) // 8192

typedef __attribute__((ext_vector_type(4))) float f32x4;
typedef __attribute__((ext_vector_type(8))) short s16x8;
typedef __attribute__((ext_vector_type(8))) unsigned short u16x8;
typedef __attribute__((ext_vector_type(4))) unsigned short u16x4;

__device__ __forceinline__ unsigned short f2bf(float f) {
    union { float f; unsigned int u; } v; v.f = f;
    unsigned int u = v.u;
    return (unsigned short)((u + 0x7FFFu + ((u >> 16) & 1u)) >> 16); // RNE
}

__device__ __forceinline__ void gl2lds16(const unsigned short* g, unsigned short* l) {
    __builtin_amdgcn_global_load_lds((const __attribute__((address_space(1))) void*)g,
                                     (__attribute__((address_space(3))) void*)l, 16, 0, 0);
}

// ---------------- fp32 -> bf16 convert: all 7 tensors in ONE launch ----------------
// blocks 0..12287: query/key/value (4096 each); 12288..14335: w_q/w_k/w_v/w_o (512 each)
__global__ __launch_bounds__(256) void cvt_all(
    const float* __restrict__ q, const float* __restrict__ k, const float* __restrict__ v,
    const float* __restrict__ wq, const float* __restrict__ wk, const float* __restrict__ wv,
    const float* __restrict__ wo,
    unsigned short* __restrict__ Xq, unsigned short* __restrict__ Xk, unsigned short* __restrict__ Xv,
    unsigned short* __restrict__ Wq, unsigned short* __restrict__ Wk, unsigned short* __restrict__ Wv,
    unsigned short* __restrict__ Wo) {
    const int bid = blockIdx.x;
    const float* src;
    unsigned short* dst;
    int blk;
    if (bid < 12288) {
        const int t = bid >> 12;
        blk = bid & 4095;
        src = (t == 0) ? q : ((t == 1) ? k : v);
        dst = (t == 0) ? Xq : ((t == 1) ? Xk : Xv);
    } else {
        const int t = (bid - 12288) >> 9;
        blk = (bid - 12288) & 511;
        src = (t == 0) ? wq : ((t == 1) ? wk : ((t == 2) ? wv : wo));
        dst = (t == 0) ? Wq : ((t == 1) ? Wk : ((t == 2) ? Wv : Wo));
    }
    const int i = (blk * 256 + threadIdx.x) * 8;
    float4 a = *(const float4*)(src + i);
    float4 b = *(const float4*)(src + i + 4);
    u16x8 r;
    r[0] = f2bf(a.x); r[1] = f2bf(a.y); r[2] = f2bf(a.z); r[3] = f2bf(a.w);
    r[4] = f2bf(b.x); r[5] = f2bf(b.y); r[6] = f2bf(b.z); r[7] = f2bf(b.w);
    *(u16x8*)(dst + i) = r;
}

// ---------------- mask int32 -> bitmask ----------------
// (separate dispatch: pm overlaps Xq, which is dead only after the QKV GEMM)
__global__ __launch_bounds__(256) void pack_mask(const int* __restrict__ m,
                                                 unsigned long long* __restrict__ pm) {
    int t = blockIdx.x * 256 + threadIdx.x;
    unsigned long long bits = __ballot(m[t] != 0);
    if ((threadIdx.x & 63) == 0) pm[t >> 6] = bits;
}

// ---------------- Fused QKV GEMM: one dispatch, grid.z selects projection --------
// z=0: Q = Xq*Wq^T+bq scaled -> (B,H,S,DK); z=1: K -> (B,H,S,DK); z=2: V -> (B,H,DK,S).
// 128x128 tile, BK=64, global_load_lds, XOR-swizzled LDS. 1536 blocks => ~3/CU.
__global__ __launch_bounds__(256) void gemm_qkv(
    const unsigned short* __restrict__ Xq, const unsigned short* __restrict__ Xk,
    const unsigned short* __restrict__ Xv,
    const unsigned short* __restrict__ Wq, const unsigned short* __restrict__ Wk,
    const unsigned short* __restrict__ Wv,
    const float* __restrict__ bq, const float* __restrict__ bk, const float* __restrict__ bv,
    float qscale,
    unsigned short* __restrict__ Qb, unsigned short* __restrict__ Kb,
    unsigned short* __restrict__ Vtb) {
    __shared__ __align__(16) unsigned short As[128 * 64];
    __shared__ __align__(16) unsigned short Bs[128 * 64];
    const int z = blockIdx.z;
    const unsigned short* A  = (z == 0) ? Xq : ((z == 1) ? Xk : Xv);
    const unsigned short* Bt = (z == 0) ? Wq : ((z == 1) ? Wk : Wv);
    const float* bias        = (z == 0) ? bq : ((z == 1) ? bk : bv);
    unsigned short* Y        = (z == 0) ? Qb : ((z == 1) ? Kb : Vtb);
    const float scale        = (z == 0) ? qscale : 1.0f;

    const int tid = threadIdx.x;
    const int wave = tid >> 6, lane = tid & 63, quad = lane >> 4, l16 = lane & 15;
    const int m0 = blockIdx.x * 128, n0 = blockIdx.y * 128;
    const int rw = (wave & 1) * 64, cw = (wave >> 1) * 64;
    const int sw = l16 & 7;

    const int srow = tid >> 3, scol = ((tid & 7) ^ (srow & 7)) * 8;
    const unsigned short* ga = A + (size_t)(m0 + srow) * 1024 + scol;
    const unsigned short* gb = Bt + (size_t)(n0 + srow) * 1024 + scol;

    f32x4 acc[4][4];
#pragma unroll
    for (int mi = 0; mi < 4; mi++)
#pragma unroll
        for (int ni = 0; ni < 4; ni++) acc[mi][ni] = (f32x4){0.f, 0.f, 0.f, 0.f};

    for (int k0 = 0; k0 < 1024; k0 += 64) {
#pragma unroll
        for (int r = 0; r < 4; r++) {
            gl2lds16(ga + (size_t)(r * 32) * 1024 + k0, &As[(r * 256 + tid) * 8]);
            gl2lds16(gb + (size_t)(r * 32) * 1024 + k0, &Bs[(r * 256 + tid) * 8]);
        }
        __syncthreads();
#pragma unroll
        for (int kki = 0; kki < 2; kki++) {
            const int xo = ((kki * 4 + quad) ^ sw) * 8;
            s16x8 af[4], bf[4];
#pragma unroll
            for (int mi = 0; mi < 4; mi++)
                af[mi] = *(const s16x8*)&As[(rw + mi * 16 + l16) * 64 + xo];
#pragma unroll
            for (int ni = 0; ni < 4; ni++)
                bf[ni] = *(const s16x8*)&Bs[(cw + ni * 16 + l16) * 64 + xo];
#pragma unroll
            for (int mi = 0; mi < 4; mi++)
#pragma unroll
                for (int ni = 0; ni < 4; ni++)
                    acc[mi][ni] = __builtin_amdgcn_mfma_f32_16x16x32_bf16(af[mi], bf[ni], acc[mi][ni], 0, 0, 0);
        }
        __syncthreads();
    }

    float bv4[4];
#pragma unroll
    for (int ni = 0; ni < 4; ni++) bv4[ni] = bias[n0 + cw + ni * 16 + l16];
#pragma unroll
    for (int mi = 0; mi < 4; mi++) {
        const int rb = m0 + rw + mi * 16 + quad * 4;
        const int b = rb >> 11, s0 = rb & 2047;
#pragma unroll
        for (int ni = 0; ni < 4; ni++) {
            const int col = n0 + cw + ni * 16 + l16;
            const int h = col >> 6, dk = col & 63;
            if (z < 2) {
#pragma unroll
                for (int i = 0; i < 4; i++)
                    Y[((size_t)(b * H_ + h) * S_ + s0 + i) * DK_ + dk] =
                        f2bf((acc[mi][ni][i] + bv4[ni]) * scale);
            } else {
                u16x4 pk;
#pragma unroll
                for (int i = 0; i < 4; i++) pk[i] = f2bf(acc[mi][ni][i] + bv4[ni]);
                *(u16x4*)&Y[((size_t)(b * H_ + h) * DK_ + dk) * S_ + s0] = pk;
            }
        }
    }
}

// ---------------- Out-proj GEMM: fp32 out M x 1024 ----------------
__global__ __launch_bounds__(256) void gemm_o(const unsigned short* __restrict__ A,
                                              const unsigned short* __restrict__ Bt,
                                              const float* __restrict__ bias,
                                              float* __restrict__ Y) {
    __shared__ __align__(16) unsigned short As[128 * 64];
    __shared__ __align__(16) unsigned short Bs[128 * 64];
    const int tid = threadIdx.x;
    const int wave = tid >> 6, lane = tid & 63, quad = lane >> 4, l16 = lane & 15;
    const int m0 = blockIdx.x * 128, n0 = blockIdx.y * 128;
    const int rw = (wave & 1) * 64, cw = (wave >> 1) * 64;
    const int sw = l16 & 7;

    const int srow = tid >> 3, scol = ((tid & 7) ^ (srow & 7)) * 8;
    const unsigned short* ga = A + (size_t)(m0 + srow) * 1024 + scol;
    const unsigned short* gb = Bt + (size_t)(n0 + srow) * 1024 + scol;

    f32x4 acc[4][4];
#pragma unroll
    for (int mi = 0; mi < 4; mi++)
#pragma unroll
        for (int ni = 0; ni < 4; ni++) acc[mi][ni] = (f32x4){0.f, 0.f, 0.f, 0.f};

    for (int k0 = 0; k0 < 1024; k0 += 64) {
#pragma unroll
        for (int r = 0; r < 4; r++) {
            gl2lds16(ga + (size_t)(r * 32) * 1024 + k0, &As[(r * 256 + tid) * 8]);
            gl2lds16(gb + (size_t)(r * 32) * 1024 + k0, &Bs[(r * 256 + tid) * 8]);
        }
        __syncthreads();
#pragma unroll
        for (int kki = 0; kki < 2; kki++) {
            const int xo = ((kki * 4 + quad) ^ sw) * 8;
            s16x8 af[4], bf[4];
#pragma unroll
            for (int mi = 0; mi < 4; mi++)
                af[mi] = *(const s16x8*)&As[(rw + mi * 16 + l16) * 64 + xo];
#pragma unroll
            for (int ni = 0; ni < 4; ni++)
                bf[ni] = *(const s16x8*)&Bs[(cw + ni * 16 + l16) * 64 + xo];
#pragma unroll
            for (int mi = 0; mi < 4; mi++)
#pragma unroll
                for (int ni = 0; ni < 4; ni++)
                    acc[mi][ni] = __builtin_amdgcn_mfma_f32_16x16x32_bf16(af[mi], bf[ni], acc[mi][ni], 0, 0, 0);
        }
        __syncthreads();
    }

    float bv4[4];
#pragma unroll
    for (int ni = 0; ni < 4; ni++) bv4[ni] = bias[n0 + cw + ni * 16 + l16];
#pragma unroll
    for (int mi = 0; mi < 4; mi++) {
        const int rb = m0 + rw + mi * 16 + quad * 4;
#pragma unroll
        for (int ni = 0; ni < 4; ni++) {
            const int col = n0 + cw + ni * 16 + l16;
#pragma unroll
            for (int i = 0; i < 4; i++)
                Y[(size_t)(rb + i) * 1024 + col] = acc[mi][ni][i] + bv4[ni];
        }
    }
}

// ---------------- Flash attention (St layout, register-P, 2-phase dbuf) ----------
// Grid (S/128, B*H), block 256 = 4 waves; wave owns 32 q rows (2 blocks of 16).
// St = K*Q^T; p = exp2(s) AND sbfe-mask; P via perm-pack + permlane swaps (in reg).
// K/V tiles AND mask regs double-buffered: mask(kt+1)+kv(kt+1) issued together,
// vmcnt(6) retires only >=1-iter-old loads => no exposed latency in steady state.
__global__ __launch_bounds__(256) void attn_kernel(const unsigned short* __restrict__ Q,
                                                   const unsigned short* __restrict__ K,
                                                   const unsigned short* __restrict__ Vt,
                                                   const unsigned long long* __restrict__ pm,
                                                   unsigned short* __restrict__ ctx) {
    __shared__ __align__(16) unsigned short Ks[2][64 * 64];
    __shared__ __align__(16) unsigned short Vs[2][64 * 64];

    const int tid = threadIdx.x;
    const int wave = tid >> 6, lane = tid & 63, quad = lane >> 4, l16 = lane & 15;
    const int bh = blockIdx.y, b = bh >> 4, h = bh & 15;
    const int q0 = blockIdx.x * 128;
    const int qbase = q0 + wave * 32;
    const int sw = l16 & 7, q4 = quad * 4;
    const int NT = S_ / 64; // 32

    const unsigned short* Kbase = K + (size_t)bh * S_ * DK_;
    const unsigned short* Vbase = Vt + (size_t)bh * DK_ * S_;

    // Q fragments (B-operand): B[n=q=l16][k=d]
    s16x8 qf[2][2];
#pragma unroll
    for (int qb = 0; qb < 2; qb++) {
        const unsigned short* qr = Q + ((size_t)bh * S_ + qbase + qb * 16 + l16) * DK_ + quad * 8;
        qf[qb][0] = *(const s16x8*)qr;
        qf[qb][1] = *(const s16x8*)(qr + 32);
    }
    const unsigned long long* pmq[2];
#pragma unroll
    for (int qb = 0; qb < 2; qb++)
        pmq[qb] = pm + ((size_t)b * S_ + qbase + qb * 16 + l16) * 32;

    s16x8 ones;
#pragma unroll
    for (int j = 0; j < 8; j++) ones[j] = (short)0x3F80; // bf16 1.0

    f32x4 oacc[2][4], lacc[2];
#pragma unroll
    for (int qb = 0; qb < 2; qb++) {
        lacc[qb] = (f32x4){0.f, 0.f, 0.f, 0.f};
#pragma unroll
        for (int ct = 0; ct < 4; ct++) oacc[qb][ct] = (f32x4){0.f, 0.f, 0.f, 0.f};
    }

    const int sr = tid >> 3, sc = ((tid & 7) ^ (sr & 7)) * 8;
    const unsigned short* Kg0 = Kbase + (size_t)sr * DK_ + sc;
    const unsigned short* Kg1 = Kbase + (size_t)(32 + sr) * DK_ + sc;
    const unsigned short* Vg0 = Vbase + (size_t)sr * S_ + sc;
    const unsigned short* Vg1 = Vbase + (size_t)(32 + sr) * S_ + sc;

    // prologue: mask(0) then kv(0) -> buffer 0 (6 outstanding vmem ops)
    uint2 mv[2][2];
    mv[0][0] = *(const uint2*)&pmq[0][0];
    mv[0][1] = *(const uint2*)&pmq[1][0];
    __builtin_amdgcn_sched_barrier(0);
    gl2lds16(Kg0, &Ks[0][tid * 8]);
    gl2lds16(Kg1, &Ks[0][2048 + tid * 8]);
    gl2lds16(Vg0, &Vs[0][tid * 8]);
    gl2lds16(Vg1, &Vs[0][2048 + tid * 8]);

#pragma unroll 2
    for (int kt = 0; kt < NT; kt++) {
        const int cur = kt & 1;
        const int nxt = cur ^ 1;

        if (kt + 1 < NT) {
            // prefetch mask(kt+1) BEFORE kv(kt+1): vmcnt(6) then hides both
            mv[nxt][0] = *(const uint2*)&pmq[0][kt + 1];
            mv[nxt][1] = *(const uint2*)&pmq[1][kt + 1];
            __builtin_amdgcn_sched_barrier(0);
            const int k1 = (kt + 1) * 64;
            gl2lds16(Kg0 + (size_t)k1 * DK_, &Ks[nxt][tid * 8]);
            gl2lds16(Kg1 + (size_t)k1 * DK_, &Ks[nxt][2048 + tid * 8]);
            gl2lds16(Vg0 + k1, &Vs[nxt][tid * 8]);
            gl2lds16(Vg1 + k1, &Vs[nxt][2048 + tid * 8]);
            asm volatile("s_waitcnt vmcnt(6)" ::: "memory"); // tile kt + mask kt done
        } else {
            asm volatile("s_waitcnt vmcnt(0)" ::: "memory");
        }
        __builtin_amdgcn_s_barrier();

        // St = K * Q^T
        f32x4 sacc[2][4];
#pragma unroll
        for (int qb = 0; qb < 2; qb++)
#pragma unroll
            for (int ct = 0; ct < 4; ct++) sacc[qb][ct] = (f32x4){0.f, 0.f, 0.f, 0.f};
#pragma unroll
        for (int kki = 0; kki < 2; kki++) {
            const int xo = ((kki * 4 + quad) ^ sw) * 8;
            s16x8 kf[4];
#pragma unroll
            for (int ct = 0; ct < 4; ct++)
                kf[ct] = *(const s16x8*)&Ks[cur][(ct * 16 + l16) * 64 + xo];
            __builtin_amdgcn_s_setprio(1);
#pragma unroll
            for (int qb = 0; qb < 2; qb++)
#pragma unroll
                for (int ct = 0; ct < 4; ct++)
                    sacc[qb][ct] = __builtin_amdgcn_mfma_f32_16x16x32_bf16(kf[ct], qf[qb][kki], sacc[qb][ct], 0, 0, 0);
            __builtin_amdgcn_s_setprio(0);
        }

        // mask (sbfe) + exp2 + perm-pack -> P pairs in registers
        unsigned pk[2][4][2];
#pragma unroll
        for (int qb = 0; qb < 2; qb++) {
            const unsigned mqx = mv[cur][qb].x >> q4;
            const unsigned mqy = mv[cur][qb].y >> q4;
#pragma unroll
            for (int ct = 0; ct < 4; ct++) {
                const unsigned mq = (ct & 2) ? mqy : mqx;
#pragma unroll
                for (int t = 0; t < 2; t++) {
                    const int pos = (ct & 1) * 16 + 2 * t;
                    const int mb0 = __builtin_amdgcn_sbfe(mq, pos, 1);     // 0 or -1
                    const int mb1 = __builtin_amdgcn_sbfe(mq, pos + 1, 1);
                    const unsigned p0 =
                        __float_as_uint(__builtin_amdgcn_exp2f(sacc[qb][ct][2 * t])) & (unsigned)mb0;
                    const unsigned p1 =
                        __float_as_uint(__builtin_amdgcn_exp2f(sacc[qb][ct][2 * t + 1])) & (unsigned)mb1;
                    pk[qb][ct][t] = __builtin_amdgcn_perm(p1, p0, 0x07060302u);
                }
            }
        }

        // O += P*V ; l += P*ones  (P rearranged quad-wise via permlane swaps)
#pragma unroll
        for (int kki = 0; kki < 2; kki++) {
            const int xo = ((kki * 4 + quad) ^ sw) * 8;
            s16x8 vf[4];
#pragma unroll
            for (int ct = 0; ct < 4; ct++)
                vf[ct] = *(const s16x8*)&Vs[cur][(ct * 16 + l16) * 64 + xo];
#pragma unroll
            for (int qb = 0; qb < 2; qb++) {
                unsigned w0 = pk[qb][2 * kki][0], w2 = pk[qb][2 * kki + 1][0];
                unsigned w1 = pk[qb][2 * kki][1], w3 = pk[qb][2 * kki + 1][1];
                asm("v_permlane32_swap_b32 %0, %1" : "+v"(w0), "+v"(w2));
                asm("v_permlane16_swap_b32 %0, %1" : "+v"(w0), "+v"(w2));
                asm("v_permlane32_swap_b32 %0, %1" : "+v"(w1), "+v"(w3));
                asm("v_permlane16_swap_b32 %0, %1" : "+v"(w1), "+v"(w3));
                union { unsigned u[4]; s16x8 v; } pfu;
                pfu.u[0] = w0; pfu.u[1] = w1; pfu.u[2] = w2; pfu.u[3] = w3;
                const s16x8 pf = pfu.v;
                __builtin_amdgcn_s_setprio(1);
#pragma unroll
                for (int ct = 0; ct < 4; ct++)
                    oacc[qb][ct] = __builtin_amdgcn_mfma_f32_16x16x32_bf16(pf, vf[ct], oacc[qb][ct], 0, 0, 0);
                lacc[qb] = __builtin_amdgcn_mfma_f32_16x16x32_bf16(pf, ones, lacc[qb], 0, 0, 0);
                __builtin_amdgcn_s_setprio(0);
            }
        }

        asm volatile("s_waitcnt lgkmcnt(0)" ::: "memory"); // my LDS reads retired
        __builtin_amdgcn_s_barrier();                      // safe to overwrite cur next iter
    }

    // epilogue
#pragma unroll
    for (int qb = 0; qb < 2; qb++) {
        f32x4 rl;
#pragma unroll
        for (int i = 0; i < 4; i++) rl[i] = 1.0f / lacc[qb][i];
#pragma unroll
        for (int ct = 0; ct < 4; ct++) {
            const int col = h * DK_ + ct * 16 + l16;
#pragma unroll
            for (int i = 0; i < 4; i++) {
                const int sg = qbase + qb * 16 + quad * 4 + i;
                ctx[((size_t)(b * S_ + sg)) * D_ + col] = f2bf(oacc[qb][ct][i] * rl[i]);
            }
        }
    }
}

// ---------------- launch ----------------
extern "C" void kernel_launch(void* const* d_in, const int* in_sizes, int n_in,
                              void* d_out, int out_size, void* d_ws, size_t ws_size,
                              hipStream_t stream) {
    const float* query = (const float*)d_in[0];
    const float* key   = (const float*)d_in[1];
    const float* value = (const float*)d_in[2];
    const int*   mask  = (const int*)d_in[3];
    const float* w_q = (const float*)d_in[4];
    const float* b_q = (const float*)d_in[5];
    const float* w_k = (const float*)d_in[6];
    const float* b_k = (const float*)d_in[7];
    const float* w_v = (const float*)d_in[8];
    const float* b_v = (const float*)d_in[9];
    const float* w_o = (const float*)d_in[10];
    const float* b_o = (const float*)d_in[11];

    char* ws = (char*)d_ws;
    const size_t XSZ = (size_t)M_ * D_ * 2;  // 16 MB
    const size_t WSZ = (size_t)D_ * D_ * 2;  // 2 MB
    unsigned short* Xq  = (unsigned short*)(ws);
    unsigned short* Xk  = (unsigned short*)(ws + XSZ);
    unsigned short* Xv  = (unsigned short*)(ws + 2 * XSZ);
    unsigned short* Wq  = (unsigned short*)(ws + 3 * XSZ);
    unsigned short* Wk  = (unsigned short*)(ws + 3 * XSZ + WSZ);
    unsigned short* Wv  = (unsigned short*)(ws + 3 * XSZ + 2 * WSZ);
    unsigned short* Wo  = (unsigned short*)(ws + 3 * XSZ + 3 * WSZ);
    unsigned short* Qb  = (unsigned short*)(ws + 3 * XSZ + 4 * WSZ);
    unsigned short* Kb  = (unsigned short*)(ws + 4 * XSZ + 4 * WSZ);
    unsigned short* Vtb = (unsigned short*)(ws + 5 * XSZ + 4 * WSZ);
    unsigned short* ctx = (unsigned short*)(ws + 6 * XSZ + 4 * WSZ);
    unsigned long long* pm = (unsigned long long*)(ws); // overlaps Xq (dead after QKV GEMM)

    // all 7 fp32->bf16 converts in one launch
    hipLaunchKernelGGL(cvt_all, dim3(14336), dim3(256), 0, stream,
                       query, key, value, w_q, w_k, w_v, w_o,
                       Xq, Xk, Xv, Wq, Wk, Wv, Wo);

    const float QSCALE = 0.125f * 1.44269504f; // fold /sqrt(DK) and log2(e) into Q
    // fused QKV projections: one dispatch, 64 x 8 x 3 = 1536 blocks
    hipLaunchKernelGGL(gemm_qkv, dim3(M_ / 128, D_ / 128, 3), dim3(256), 0, stream,
                       Xq, Xk, Xv, Wq, Wk, Wv, b_q, b_k, b_v, QSCALE, Qb, Kb, Vtb);

    // pack mask AFTER QKV GEMM (pm overlaps Xq)
    hipLaunchKernelGGL(pack_mask, dim3((B_ * S_ * S_) / 256), dim3(256), 0, stream, mask, pm);

    hipLaunchKernelGGL(attn_kernel, dim3(S_ / 128, B_ * H_), dim3(256), 0, stream,
                       Qb, Kb, Vtb, pm, ctx);

    hipLaunchKernelGGL(gemm_o, dim3(M_ / 128, D_ / 128), dim3(256), 0, stream,
                       ctx, Wo, b_o, (float*)d_out);
}